// Round 22
// baseline (165.085 us; speedup 1.0000x reference)
//
#include <hip/hip_runtime.h>
#include <hip/hip_bf16.h>
#include <cstdint>

typedef float f32x4 __attribute__((ext_vector_type(4)));
typedef __bf16 bf16x8 __attribute__((ext_vector_type(8)));

#define BS 128
#define NSP 196
#define NTM 32
#define DDIM 768

__device__ inline ushort4 f4_to_bf4(float4 v)
{
    ushort4 u;
    u.x = __builtin_bit_cast(unsigned short, (__bf16)v.x);
    u.y = __builtin_bit_cast(unsigned short, (__bf16)v.y);
    u.z = __builtin_bit_cast(unsigned short, (__bf16)v.z);
    u.w = __builtin_bit_cast(unsigned short, (__bf16)v.w);
    return u;
}

__device__ inline bf16x8 f4x2_to_bf8(float4 lo, float4 hi)
{
    bf16x8 r;
    r[0] = (__bf16)lo.x; r[1] = (__bf16)lo.y; r[2] = (__bf16)lo.z; r[3] = (__bf16)lo.w;
    r[4] = (__bf16)hi.x; r[5] = (__bf16)hi.y; r[6] = (__bf16)hi.z; r[7] = (__bf16)hi.w;
    return r;
}

__device__ inline float sumsq4(float4 a)
{
    return fmaf(a.x, a.x, fmaf(a.y, a.y, fmaf(a.z, a.z, a.w * a.w)));
}

// sum over the 16-lane DPP row; every lane gets the total.
__device__ inline float row16_sum(float x)
{
    int t;
    t = __builtin_amdgcn_update_dpp(0, __builtin_bit_cast(int, x), 0x121, 0xf, 0xf, true);
    x += __builtin_bit_cast(float, t);
    t = __builtin_amdgcn_update_dpp(0, __builtin_bit_cast(int, x), 0x122, 0xf, 0xf, true);
    x += __builtin_bit_cast(float, t);
    t = __builtin_amdgcn_update_dpp(0, __builtin_bit_cast(int, x), 0x124, 0xf, 0xf, true);
    x += __builtin_bit_cast(float, t);
    t = __builtin_amdgcn_update_dpp(0, __builtin_bit_cast(int, x), 0x128, 0xf, 0xf, true);
    x += __builtin_bit_cast(float, t);
    return x;
}

// ====== prep2: row inv-norms for all 4 inputs + bf16 copies of spatial ======
// 2 rows per wave (6 independent loads in flight) -> BW-bound, not latency.
// grid: [0,3136) sp1, [3136,6272) sp2, [6272,6784) tm1, [6784,7296) tm2
__global__ __launch_bounds__(256)
void prep2_kernel(const float* __restrict__ sp1, const float* __restrict__ sp2,
                  const float* __restrict__ tm1, const float* __restrict__ tm2,
                  float* __restrict__ inx_sp, float* __restrict__ iny_sp,
                  float* __restrict__ inx_tm, float* __restrict__ iny_tm,
                  __bf16* __restrict__ X16, __bf16* __restrict__ Y16)
{
    int B = blockIdx.x;
    const float* src; float* inv; __bf16* dst;
    if (B < 3136)      {            src = sp1; inv = inx_sp; dst = X16; }
    else if (B < 6272) { B -= 3136; src = sp2; inv = iny_sp; dst = Y16; }
    else if (B < 6784) { B -= 6272; src = tm1; inv = inx_tm; dst = nullptr; }
    else               { B -= 6784; src = tm2; inv = iny_tm; dst = nullptr; }

    const int wv = threadIdx.x >> 6, lane = threadIdx.x & 63;
    const int r0 = B * 8 + wv * 2;
    const int r1 = r0 + 1;
    const float4* p0 = reinterpret_cast<const float4*>(src + (size_t)r0 * DDIM);
    const float4* p1 = reinterpret_cast<const float4*>(src + (size_t)r1 * DDIM);

    float4 v0[3], v1[3];
#pragma unroll
    for (int c = 0; c < 3; ++c) {
        v0[c] = p0[lane + 64 * c];
        v1[c] = p1[lane + 64 * c];
    }
    float s0 = 0.f, s1 = 0.f;
#pragma unroll
    for (int c = 0; c < 3; ++c) {
        s0 += sumsq4(v0[c]);
        s1 += sumsq4(v1[c]);
    }
#pragma unroll
    for (int off = 32; off; off >>= 1) {
        s0 += __shfl_xor(s0, off, 64);
        s1 += __shfl_xor(s1, off, 64);
    }
    if (lane == 0) {
        inv[r0] = 1.0f / (sqrtf(s0) + 1e-12f);
        inv[r1] = 1.0f / (sqrtf(s1) + 1e-12f);
    }
    if (dst) {
#pragma unroll
        for (int c = 0; c < 3; ++c) {
            *reinterpret_cast<ushort4*>(&dst[(size_t)r0 * DDIM + lane * 4 + 256 * c]) = f4_to_bf4(v0[c]);
            *reinterpret_cast<ushort4*>(&dst[(size_t)r1 * DDIM + lane * 4 + 256 * c]) = f4_to_bf4(v1[c]);
        }
    }
}

// ============ spatial cost GEMM, bf16 inputs (R8-verified, L3-hot) ===========
#define GA_LDS 18432
__global__ __launch_bounds__(448)
void cost_gemm_sp16(const __bf16* __restrict__ X, const __bf16* __restrict__ Y,
                    const float* __restrict__ invx, const float* __restrict__ invy,
                    __bf16* __restrict__ Aout)
{
    __shared__ __bf16 lds[2 * GA_LDS];

    const int flat  = blockIdx.x;
    const int xcd   = flat & 7;
    const int s     = flat >> 3;
    const int b     = xcd * 16 + (s >> 2);
    const int ctile = s & 3;
    const int n0    = (ctile < 3) ? ctile * 64 : 132;

    const int tid  = threadIdx.x;
    const int w    = tid >> 6, lane = tid & 63;
    const int q    = lane >> 4, l16 = lane & 15;
    const int srow = tid >> 3;
    const int sslt = tid & 7;

    const __bf16* Yb = Y + (size_t)b * NSP * DDIM;

    bf16x8 aR[4], bR, b2R;

    auto LOADS = [&](int k0) {
#pragma unroll
        for (int p = 0; p < 4; ++p) {
            int gr = b * NSP + srow + 56 * p;
            gr = min(gr, BS * NSP - 1);
            aR[p] = *reinterpret_cast<const bf16x8*>(X + (size_t)gr * DDIM + k0 + sslt * 8);
        }
        bR = *reinterpret_cast<const bf16x8*>(Yb + (size_t)(n0 + srow) * DDIM + k0 + sslt * 8);
        if (tid < 64)
            b2R = *reinterpret_cast<const bf16x8*>(Yb + (size_t)(n0 + 56 + srow) * DDIM + k0 + sslt * 8);
    };
    auto WRITES = [&](int buf) {
#pragma unroll
        for (int p = 0; p < 4; ++p) {
            int r = srow + 56 * p;
            *reinterpret_cast<bf16x8*>(&lds[buf * GA_LDS + r * 64 + ((sslt ^ (r & 7)) << 3)]) = aR[p];
        }
        {
            int r = srow;
            *reinterpret_cast<bf16x8*>(&lds[buf * GA_LDS + 14336 + r * 64 + ((sslt ^ (r & 7)) << 3)]) = bR;
        }
        if (tid < 64) {
            int r = 56 + srow;
            *reinterpret_cast<bf16x8*>(&lds[buf * GA_LDS + 14336 + r * 64 + ((sslt ^ (r & 7)) << 3)]) = b2R;
        }
    };

    f32x4 acc[2][4];
#pragma unroll
    for (int i = 0; i < 2; ++i)
#pragma unroll
        for (int j = 0; j < 4; ++j) acc[i][j] = f32x4{0.f, 0.f, 0.f, 0.f};

    LOADS(0);
    int buf = 0;
    for (int kt = 0; kt < 12; ++kt) {
        WRITES(buf);
        if (kt < 11) LOADS((kt + 1) * 64);
        __syncthreads();
#pragma unroll
        for (int ks = 0; ks < 2; ++ks) {
            bf16x8 af[2], bf[4];
#pragma unroll
            for (int rt = 0; rt < 2; ++rt) {
                int r = w * 32 + rt * 16 + l16;
                af[rt] = *reinterpret_cast<const bf16x8*>(
                    &lds[buf * GA_LDS + r * 64 + (((ks * 4 + q) ^ (r & 7)) << 3)]);
            }
#pragma unroll
            for (int ct = 0; ct < 4; ++ct) {
                int r = ct * 16 + l16;
                bf[ct] = *reinterpret_cast<const bf16x8*>(
                    &lds[buf * GA_LDS + 14336 + r * 64 + (((ks * 4 + q) ^ (r & 7)) << 3)]);
            }
#pragma unroll
            for (int ct = 0; ct < 4; ++ct)
#pragma unroll
                for (int rt = 0; rt < 2; ++rt)
                    acc[rt][ct] = __builtin_amdgcn_mfma_f32_16x16x32_bf16(af[rt], bf[ct], acc[rt][ct], 0, 0, 0);
        }
        __syncthreads();
        buf ^= 1;
    }

    float ivy[4];
#pragma unroll
    for (int ct = 0; ct < 4; ++ct) ivy[ct] = invy[b * NSP + n0 + ct * 16 + l16];
#pragma unroll
    for (int rt = 0; rt < 2; ++rt)
#pragma unroll
        for (int rr = 0; rr < 4; ++rr) {
            int i = w * 32 + rt * 16 + q * 4 + rr;
            if (i < NSP) {
                float ivx = invx[b * NSP + i];
#pragma unroll
                for (int ct = 0; ct < 4; ++ct) {
                    int j = n0 + ct * 16 + l16;
                    float cs = acc[rt][ct][rr] * ivx * ivy[ct];
                    Aout[(size_t)b * 65536 + (size_t)i * 256 + j] = (__bf16)__expf(2.0f * cs - 2.0f);
                }
            }
        }
}

// ============== spatial cost GEMM fallback, f32 (R16-verified) ==============
__global__ __launch_bounds__(448)
void cost_gemm_sp2(const float* __restrict__ X, const float* __restrict__ Y,
                   __bf16* __restrict__ Aout)
{
    __shared__ __bf16 lds[11264];
    float* ldsF = reinterpret_cast<float*>(lds);

    const int flat  = blockIdx.x;
    const int xcd   = flat & 7;
    const int s     = flat >> 3;
    const int b     = xcd * 16 + (s >> 3);
    const int rem   = s & 7;
    const int r0    = (rem >> 2) * 112;
    const int ct_   = rem & 3;
    const int n0    = (ct_ < 3) ? ct_ * 64 : 132;

    const int tid  = threadIdx.x;
    const int w    = tid >> 6, lane = tid & 63;
    const int q    = lane >> 4, l16 = lane & 15;
    const int srow = tid >> 3;
    const int sslt = tid & 7;

    const float* Yb = Y + (size_t)b * NSP * DDIM;

    float4 aL[2], aH[2], bL, bH, b2L, b2H;
    float ssA[2] = {0.f, 0.f};
    float ssB = 0.f, ssB2 = 0.f;

    auto LOADS = [&](int k0) {
#pragma unroll
        for (int p = 0; p < 2; ++p) {
            int gr = b * NSP + r0 + srow + 56 * p;
            gr = min(gr, BS * NSP - 1);
            const float* sp = X + (size_t)gr * DDIM + k0 + sslt * 8;
            aL[p] = *reinterpret_cast<const float4*>(sp);
            aH[p] = *reinterpret_cast<const float4*>(sp + 4);
        }
        {
            const float* sp = Yb + (size_t)(n0 + srow) * DDIM + k0 + sslt * 8;
            bL = *reinterpret_cast<const float4*>(sp);
            bH = *reinterpret_cast<const float4*>(sp + 4);
        }
        if (tid < 64) {
            const float* sp = Yb + (size_t)(n0 + 56 + srow) * DDIM + k0 + sslt * 8;
            b2L = *reinterpret_cast<const float4*>(sp);
            b2H = *reinterpret_cast<const float4*>(sp + 4);
        }
    };
    auto WRITES = [&]() {
#pragma unroll
        for (int p = 0; p < 2; ++p) {
            int r = srow + 56 * p;
            ssA[p] += sumsq4(aL[p]) + sumsq4(aH[p]);
            *reinterpret_cast<bf16x8*>(&lds[r * 64 + ((sslt ^ (r & 7)) << 3)]) =
                f4x2_to_bf8(aL[p], aH[p]);
        }
        {
            int r = srow;
            ssB += sumsq4(bL) + sumsq4(bH);
            *reinterpret_cast<bf16x8*>(&lds[7168 + r * 64 + ((sslt ^ (r & 7)) << 3)]) =
                f4x2_to_bf8(bL, bH);
        }
        if (tid < 64) {
            int r = 56 + srow;
            ssB2 += sumsq4(b2L) + sumsq4(b2H);
            *reinterpret_cast<bf16x8*>(&lds[7168 + r * 64 + ((sslt ^ (r & 7)) << 3)]) =
                f4x2_to_bf8(b2L, b2H);
        }
    };

    f32x4 acc[4];
#pragma unroll
    for (int j = 0; j < 4; ++j) acc[j] = f32x4{0.f, 0.f, 0.f, 0.f};

    LOADS(0);
    for (int kt = 0; kt < 12; ++kt) {
        if (kt) __syncthreads();
        WRITES();
        __syncthreads();
        if (kt < 11) LOADS((kt + 1) * 64);
#pragma unroll
        for (int ks = 0; ks < 2; ++ks) {
            bf16x8 af, bf[4];
            {
                int r = w * 16 + l16;
                af = *reinterpret_cast<const bf16x8*>(
                    &lds[r * 64 + (((ks * 4 + q) ^ (r & 7)) << 3)]);
            }
#pragma unroll
            for (int ct = 0; ct < 4; ++ct) {
                int r = ct * 16 + l16;
                bf[ct] = *reinterpret_cast<const bf16x8*>(
                    &lds[7168 + r * 64 + (((ks * 4 + q) ^ (r & 7)) << 3)]);
            }
#pragma unroll
            for (int ct = 0; ct < 4; ++ct)
                acc[ct] = __builtin_amdgcn_mfma_f32_16x16x32_bf16(af, bf[ct], acc[ct], 0, 0, 0);
        }
    }
    __syncthreads();

#pragma unroll
    for (int p = 0; p < 2; ++p) ldsF[(srow + 56 * p) * 8 + sslt] = ssA[p];
    ldsF[896 + srow * 8 + sslt] = ssB;
    if (tid < 64) ldsF[896 + (56 + srow) * 8 + sslt] = ssB2;
    __syncthreads();

    float ivy[4];
#pragma unroll
    for (int ct = 0; ct < 4; ++ct) {
        int jr = ct * 16 + l16;
        f32x4 s0 = *reinterpret_cast<const f32x4*>(&ldsF[896 + jr * 8]);
        f32x4 s1 = *reinterpret_cast<const f32x4*>(&ldsF[896 + jr * 8 + 4]);
        float ss = (s0.x + s0.y) + (s0.z + s0.w) + (s1.x + s1.y) + (s1.z + s1.w);
        ivy[ct] = 1.0f / (sqrtf(ss) + 1e-12f);
    }
#pragma unroll
    for (int rr = 0; rr < 4; ++rr) {
        int i = w * 16 + q * 4 + rr;
        int gi = r0 + i;
        if (gi < NSP) {
            f32x4 s0 = *reinterpret_cast<const f32x4*>(&ldsF[i * 8]);
            f32x4 s1 = *reinterpret_cast<const f32x4*>(&ldsF[i * 8 + 4]);
            float ss = (s0.x + s0.y) + (s0.z + s0.w) + (s1.x + s1.y) + (s1.z + s1.w);
            float ivx = 1.0f / (sqrtf(ss) + 1e-12f);
#pragma unroll
            for (int ct = 0; ct < 4; ++ct) {
                float cs = acc[ct][rr] * ivx * ivy[ct];
                Aout[(size_t)b * 65536 + (size_t)gi * 256 + (n0 + ct * 16 + l16)] =
                    (__bf16)__expf(2.0f * cs - 2.0f);
            }
        }
    }
}

// ---------------- temporal cost GEMM (f32 in/out) ----------------
template<int WROWS, int NWAVES, int BN, int NPTS>
__global__ __launch_bounds__(NWAVES * 64)
void cost_gemm(const float* __restrict__ X, const float* __restrict__ Y,
               const float* __restrict__ invx, const float* __restrict__ invy,
               float* __restrict__ Aout)
{
    constexpr int MT = WROWS * NWAVES;
    constexpr int CT = BN / 16;
    constexpr int RT = WROWS / 16;
    constexpr int KP = 40;
    constexpr int NTH = NWAVES * 64;
    __shared__ __bf16 As[MT][KP];
    __shared__ __bf16 Bs[BN][KP];

    const int b    = blockIdx.y;
    const int row0 = blockIdx.x * MT;
    const int tid  = threadIdx.x;
    const int w    = tid >> 6, lane = tid & 63;
    const int q    = lane >> 4, l16 = lane & 15;
    const float* Xb = X + (size_t)b * NPTS * DDIM;
    const float* Yb = Y + (size_t)b * NPTS * DDIM;

    f32x4 acc[RT][CT];
#pragma unroll
    for (int i = 0; i < RT; ++i)
#pragma unroll
        for (int j = 0; j < CT; ++j) acc[i][j] = f32x4{0.f, 0.f, 0.f, 0.f};

    for (int k0 = 0; k0 < DDIM; k0 += 32) {
        __syncthreads();
        for (int idx = tid * 4; idx < MT * 32; idx += NTH * 4) {
            int r = idx >> 5, kk = idx & 31;
            int gr = row0 + r;
            float4 v = {0.f, 0.f, 0.f, 0.f};
            if (gr < NPTS) v = *reinterpret_cast<const float4*>(Xb + (size_t)gr * DDIM + k0 + kk);
            *reinterpret_cast<ushort4*>(&As[r][kk]) = f4_to_bf4(v);
        }
        for (int idx = tid * 4; idx < BN * 32; idx += NTH * 4) {
            int r = idx >> 5, kk = idx & 31;
            float4 v = {0.f, 0.f, 0.f, 0.f};
            if (r < NPTS) v = *reinterpret_cast<const float4*>(Yb + (size_t)r * DDIM + k0 + kk);
            *reinterpret_cast<ushort4*>(&Bs[r][kk]) = f4_to_bf4(v);
        }
        __syncthreads();

        bf16x8 af[RT];
#pragma unroll
        for (int rt = 0; rt < RT; ++rt)
            af[rt] = *reinterpret_cast<const bf16x8*>(&As[w * WROWS + rt * 16 + l16][q * 8]);
#pragma unroll
        for (int ct = 0; ct < CT; ++ct) {
            bf16x8 bfr = *reinterpret_cast<const bf16x8*>(&Bs[ct * 16 + l16][q * 8]);
#pragma unroll
            for (int rt = 0; rt < RT; ++rt)
                acc[rt][ct] = __builtin_amdgcn_mfma_f32_16x16x32_bf16(af[rt], bfr, acc[rt][ct], 0, 0, 0);
        }
    }

#pragma unroll
    for (int rt = 0; rt < RT; ++rt)
#pragma unroll
        for (int ct = 0; ct < CT; ++ct)
#pragma unroll
            for (int rr = 0; rr < 4; ++rr) {
                int i = row0 + w * WROWS + rt * 16 + q * 4 + rr;
                int j = ct * 16 + l16;
                if (i < NPTS && j < NPTS) {
                    float g  = acc[rt][ct][rr];
                    float cs = g * invx[b * NPTS + i] * invy[b * NPTS + j];
                    Aout[(size_t)b * NPTS * NPTS + (size_t)i * NPTS + j] = expf(-2.0f * (1.0f - cs));
                }
            }
}

// ====== fused IPOT (R16-verified): DPP rowsum, 512 thr, A in LDS ======
__global__ __launch_bounds__(512, 1)
void ipot_dpp(const __bf16* __restrict__ Asp, const float* __restrict__ Atm,
              float* __restrict__ out)
{
    __shared__ __bf16 Alds[224 * 256];    // 114,688 B
    __shared__ float  cpart[32 * 260];    //  33,280 B
    __shared__ float  svec[2][272];
    __shared__ float  wsum[8];

    const int B = blockIdx.x;
    if (B >= 128) {
        if (threadIdx.x >= 64) return;
        const int b = B - 128;
        const float* Ab = Atm + (size_t)b * NTM * NTM;
        const int lane = threadIdx.x;
        const int rh = lane >> 5, cj = lane & 31;
        constexpr float MIU = 1.f / NTM;
        float A[16], P[16];
#pragma unroll
        for (int k = 0; k < 16; ++k) {
            A[k] = Ab[(rh + 2 * k) * NTM + cj];
            P[k] = 1.f;
        }
        float sv = MIU;
        for (int it = 0; it < 20; ++it) {
#pragma unroll
            for (int k = 0; k < 16; ++k) {
                P[k] *= A[k];
                float acc = row16_sum(P[k] * sv);
                acc += __shfl_xor(acc, 16);
                P[k] *= MIU * __builtin_amdgcn_rcpf(acc + 1e-6f);
            }
            float cssum = 0.f;
#pragma unroll
            for (int k = 0; k < 16; ++k) cssum += P[k];
            cssum += __shfl_xor(cssum, 32);
            float sg = MIU * __builtin_amdgcn_rcpf(cssum + 1e-6f);
#pragma unroll
            for (int k = 0; k < 16; ++k) P[k] *= sg;
            sv = sg;
        }
        float acc = 0.f;
#pragma unroll
        for (int k = 0; k < 16; ++k)
            acc = fmaf(P[k], -0.5f * __logf(A[k]), acc);
        acc = row16_sum(acc);
        acc += __shfl_xor(acc, 16);
        acc += __shfl_xor(acc, 32);
        if (lane == 0) atomicAdd(out, -acc * (1.f / BS));
        return;
    }

    const int b = (B & 7) * 16 + (B >> 3);
    const __bf16* Ab = Asp + (size_t)b * 65536;
    const int tid = threadIdx.x;
    const int w = tid >> 6, lane = tid & 63;
    const int rq = lane >> 4, cl = lane & 15;
    const int g = w * 4 + rq;
    const int colbase = cl * 8;
    constexpr float MIU = 1.f / NSP;

    for (int idx = tid; idx < NSP * 32; idx += 512) {
        int r = idx >> 5, c = idx & 31;
        bf16x8 v;
#pragma unroll
        for (int i = 0; i < 8; ++i) v[i] = (__bf16)0.f;
        if (c < 25) {
            v = *reinterpret_cast<const bf16x8*>(&Ab[(size_t)r * 256 + c * 8]);
            if (c == 24) { v[4] = (__bf16)0.f; v[5] = (__bf16)0.f; v[6] = (__bf16)0.f; v[7] = (__bf16)0.f; }
        }
        *reinterpret_cast<bf16x8*>(&Alds[r * 256 + c * 8]) = v;
    }
    {
        ushort4 z = {0, 0, 0, 0};
        for (int idx = tid; idx < 28 * 64; idx += 512) {
            int r = 196 + (idx >> 6), c4 = (idx & 63) << 2;
            *reinterpret_cast<ushort4*>(&Alds[r * 256 + c4]) = z;
        }
    }
    __syncthreads();

    float P[7][16];
#pragma unroll
    for (int k = 0; k < 7; ++k)
#pragma unroll
        for (int e = 0; e < 16; ++e) P[k][e] = 1.f;

    float sr[16];
#pragma unroll
    for (int e = 0; e < 16; ++e) {
        int j = (e < 8) ? (colbase + e) : (colbase + 128 + (e - 8));
        sr[e] = (j < NSP) ? MIU : 0.f;
    }

    for (int it = 0; it < 20; ++it) {
        float cs[16];
#pragma unroll
        for (int e = 0; e < 16; ++e) cs[e] = 0.f;

#pragma unroll
        for (int k = 0; k < 7; ++k) {
            const __bf16* ap = &Alds[(g + 32 * k) * 256 + colbase];
            bf16x8 a0 = *reinterpret_cast<const bf16x8*>(ap);
            bf16x8 a1 = *reinterpret_cast<const bf16x8*>(ap + 128);
            float r0 = 0.f, r1 = 0.f;
#pragma unroll
            for (int e = 0; e < 8; ++e) {
                P[k][e] *= (float)a0[e];
                r0 = fmaf(P[k][e], sr[e], r0);
            }
#pragma unroll
            for (int e = 0; e < 8; ++e) {
                P[k][8 + e] *= (float)a1[e];
                r1 = fmaf(P[k][8 + e], sr[8 + e], r1);
            }
            float racc = row16_sum(r0 + r1);
            float delta = MIU * __builtin_amdgcn_rcpf(racc + 1e-6f);
#pragma unroll
            for (int e = 0; e < 16; ++e) {
                P[k][e] *= delta;
                cs[e] += P[k][e];
            }
        }
        {
            float* cp = &cpart[g * 260 + colbase];
            *reinterpret_cast<f32x4*>(cp)     = f32x4{cs[0], cs[1], cs[2], cs[3]};
            *reinterpret_cast<f32x4*>(cp + 4) = f32x4{cs[4], cs[5], cs[6], cs[7]};
            float* cp2 = cp + 128;
            *reinterpret_cast<f32x4*>(cp2)     = f32x4{cs[8], cs[9], cs[10], cs[11]};
            *reinterpret_cast<f32x4*>(cp2 + 4) = f32x4{cs[12], cs[13], cs[14], cs[15]};
        }
        __syncthreads();
        if (tid < 256) {
            float s0 = 0.f, s1 = 0.f, s2 = 0.f, s3 = 0.f;
#pragma unroll
            for (int gg = 0; gg < 32; gg += 4) {
                s0 += cpart[(gg + 0) * 260 + tid];
                s1 += cpart[(gg + 1) * 260 + tid];
                s2 += cpart[(gg + 2) * 260 + tid];
                s3 += cpart[(gg + 3) * 260 + tid];
            }
            float sum = (s0 + s1) + (s2 + s3);
            svec[it & 1][tid] = (tid < NSP) ? (MIU * __builtin_amdgcn_rcpf(sum + 1e-6f)) : 0.f;
        }
        __syncthreads();
        {
            const float* sv = svec[it & 1];
            f32x4 t0 = *reinterpret_cast<const f32x4*>(&sv[colbase]);
            f32x4 t1 = *reinterpret_cast<const f32x4*>(&sv[colbase + 4]);
            f32x4 t2 = *reinterpret_cast<const f32x4*>(&sv[colbase + 128]);
            f32x4 t3 = *reinterpret_cast<const f32x4*>(&sv[colbase + 132]);
            sr[0] = t0.x; sr[1] = t0.y; sr[2] = t0.z; sr[3] = t0.w;
            sr[4] = t1.x; sr[5] = t1.y; sr[6] = t1.z; sr[7] = t1.w;
            sr[8] = t2.x; sr[9] = t2.y; sr[10] = t2.z; sr[11] = t2.w;
            sr[12] = t3.x; sr[13] = t3.y; sr[14] = t3.z; sr[15] = t3.w;
        }
#pragma unroll
        for (int k = 0; k < 7; ++k)
#pragma unroll
            for (int e = 0; e < 16; ++e) P[k][e] *= sr[e];
    }

    float acc = 0.f;
#pragma unroll
    for (int k = 0; k < 7; ++k) {
        const __bf16* ap = &Alds[(g + 32 * k) * 256 + colbase];
        bf16x8 a0 = *reinterpret_cast<const bf16x8*>(ap);
        bf16x8 a1 = *reinterpret_cast<const bf16x8*>(ap + 128);
#pragma unroll
        for (int e = 0; e < 8; ++e) {
            acc = fmaf(P[k][e],     -0.5f * __logf(fmaxf((float)a0[e], 1e-30f)), acc);
            acc = fmaf(P[k][8 + e], -0.5f * __logf(fmaxf((float)a1[e], 1e-30f)), acc);
        }
    }
    acc = row16_sum(acc);
    acc += __shfl_xor(acc, 16);
    acc += __shfl_xor(acc, 32);
    if (lane == 0) wsum[w] = acc;
    __syncthreads();
    if (tid == 0) {
        float t = 0.f;
#pragma unroll
        for (int i = 0; i < 8; ++i) t += wsum[i];
        atomicAdd(out, -t * (1.f / BS));
    }
}

extern "C" void kernel_launch(void* const* d_in, const int* in_sizes, int n_in,
                              void* d_out, int out_size, void* d_ws, size_t ws_size,
                              hipStream_t stream)
{
    const float* sp1 = (const float*)d_in[0];
    const float* sp2 = (const float*)d_in[1];
    const float* tm1 = (const float*)d_in[2];
    const float* tm2 = (const float*)d_in[3];
    float* out = (float*)d_out;
    float* ws  = (float*)d_ws;

    float* inx_sp = ws;                          // 25088
    float* iny_sp = inx_sp + BS * NSP;           // 25088
    float* inx_tm = iny_sp + BS * NSP;           // 4096
    float* iny_tm = inx_tm + BS * NTM;           // 4096
    float* A_tm   = iny_tm + BS * NTM;           // 131072 f32
    __bf16* A_sp  = (__bf16*)(ws + 189440);      // 33,554,432 B
    char*   base  = (char*)d_ws;
    __bf16* X16   = (__bf16*)(base + 34312192);  // 38,535,168 B
    __bf16* Y16   = (__bf16*)(base + 72847360);  // 38,535,168 B
    const size_t NEED = 111382528;
    const bool fast = (ws_size >= NEED);

    prep2_kernel<<<dim3(7296), 256, 0, stream>>>(sp1, sp2, tm1, tm2,
                                                 inx_sp, iny_sp, inx_tm, iny_tm,
                                                 fast ? X16 : nullptr, fast ? Y16 : nullptr);

    if (fast)
        cost_gemm_sp16<<<dim3(512), 448, 0, stream>>>(X16, Y16, inx_sp, iny_sp, A_sp);
    else
        cost_gemm_sp2<<<dim3(1024), 448, 0, stream>>>(sp1, sp2, A_sp);

    cost_gemm<16, 2, 32, NTM><<<dim3(1, BS), 128, 0, stream>>>(tm1, tm2, inx_tm, iny_tm, A_tm);

    (void)hipMemsetAsync(d_out, 0, sizeof(float), stream);

    ipot_dpp<<<dim3(256), 512, 0, stream>>>(A_sp, A_tm, out);
}

// Round 23
// 154.620 us; speedup vs baseline: 1.0677x; 1.0677x over previous
//
#include <hip/hip_runtime.h>
#include <hip/hip_bf16.h>
#include <cstdint>

typedef float f32x4 __attribute__((ext_vector_type(4)));
typedef __bf16 bf16x8 __attribute__((ext_vector_type(8)));

#define BS 128
#define NSP 196
#define NTM 32
#define DDIM 768

__device__ inline ushort4 f4_to_bf4(float4 v)
{
    ushort4 u;
    u.x = __builtin_bit_cast(unsigned short, (__bf16)v.x);
    u.y = __builtin_bit_cast(unsigned short, (__bf16)v.y);
    u.z = __builtin_bit_cast(unsigned short, (__bf16)v.z);
    u.w = __builtin_bit_cast(unsigned short, (__bf16)v.w);
    return u;
}

__device__ inline bf16x8 f4x2_to_bf8(float4 lo, float4 hi)
{
    bf16x8 r;
    r[0] = (__bf16)lo.x; r[1] = (__bf16)lo.y; r[2] = (__bf16)lo.z; r[3] = (__bf16)lo.w;
    r[4] = (__bf16)hi.x; r[5] = (__bf16)hi.y; r[6] = (__bf16)hi.z; r[7] = (__bf16)hi.w;
    return r;
}

__device__ inline float sumsq4(float4 a)
{
    return fmaf(a.x, a.x, fmaf(a.y, a.y, fmaf(a.z, a.z, a.w * a.w)));
}

// sum over the 16-lane DPP row; every lane gets the total.
__device__ inline float row16_sum(float x)
{
    int t;
    t = __builtin_amdgcn_update_dpp(0, __builtin_bit_cast(int, x), 0x121, 0xf, 0xf, true);
    x += __builtin_bit_cast(float, t);
    t = __builtin_amdgcn_update_dpp(0, __builtin_bit_cast(int, x), 0x122, 0xf, 0xf, true);
    x += __builtin_bit_cast(float, t);
    t = __builtin_amdgcn_update_dpp(0, __builtin_bit_cast(int, x), 0x124, 0xf, 0xf, true);
    x += __builtin_bit_cast(float, t);
    t = __builtin_amdgcn_update_dpp(0, __builtin_bit_cast(int, x), 0x128, 0xf, 0xf, true);
    x += __builtin_bit_cast(float, t);
    return x;
}

// ---------------- temporal row inverse-norms only ----------------
__global__ __launch_bounds__(256)
void tm_norm_kernel(const float* __restrict__ tm1, const float* __restrict__ tm2,
                    float* __restrict__ inx_tm, float* __restrict__ iny_tm)
{
    int B = blockIdx.x;
    const float* src; float* inv;
    if (B < 1024) { src = tm1; inv = inx_tm; }
    else          { B -= 1024; src = tm2; inv = iny_tm; }
    const int row  = B * 4 + (threadIdx.x >> 6);
    const int lane = threadIdx.x & 63;
    const float4* p = reinterpret_cast<const float4*>(src + (size_t)row * DDIM);
    float ss = 0.f;
#pragma unroll
    for (int c = 0; c < 3; ++c) ss += sumsq4(p[lane + 64 * c]);
#pragma unroll
    for (int off = 32; off; off >>= 1) ss += __shfl_xor(ss, off, 64);
    if (lane == 0) inv[row] = 1.0f / (sqrtf(ss) + 1e-12f);
}

// ============== spatial cost GEMM (verified R16: 84us) ==============
__global__ __launch_bounds__(448)
void cost_gemm_sp2(const float* __restrict__ X, const float* __restrict__ Y,
                   __bf16* __restrict__ Aout)
{
    __shared__ __bf16 lds[11264];          // A 112*64 + B 64*64 = 22,528 B
    float* ldsF = reinterpret_cast<float*>(lds);

    const int flat  = blockIdx.x;
    const int xcd   = flat & 7;
    const int s     = flat >> 3;           // 0..127
    const int b     = xcd * 16 + (s >> 3);
    const int rem   = s & 7;
    const int r0    = (rem >> 2) * 112;    // 0 or 112
    const int ct_   = rem & 3;
    const int n0    = (ct_ < 3) ? ct_ * 64 : 132;

    const int tid  = threadIdx.x;
    const int w    = tid >> 6, lane = tid & 63;
    const int q    = lane >> 4, l16 = lane & 15;
    const int srow = tid >> 3;          // 0..55
    const int sslt = tid & 7;           // 0..7

    const float* Yb = Y + (size_t)b * NSP * DDIM;

    float4 aL[2], aH[2], bL, bH, b2L, b2H;
    float ssA[2] = {0.f, 0.f};
    float ssB = 0.f, ssB2 = 0.f;

    auto LOADS = [&](int k0) {
#pragma unroll
        for (int p = 0; p < 2; ++p) {
            int gr = b * NSP + r0 + srow + 56 * p;
            gr = min(gr, BS * NSP - 1);              // clamp; masked at store
            const float* sp = X + (size_t)gr * DDIM + k0 + sslt * 8;
            aL[p] = *reinterpret_cast<const float4*>(sp);
            aH[p] = *reinterpret_cast<const float4*>(sp + 4);
        }
        {
            const float* sp = Yb + (size_t)(n0 + srow) * DDIM + k0 + sslt * 8;
            bL = *reinterpret_cast<const float4*>(sp);
            bH = *reinterpret_cast<const float4*>(sp + 4);
        }
        if (tid < 64) {
            const float* sp = Yb + (size_t)(n0 + 56 + srow) * DDIM + k0 + sslt * 8;
            b2L = *reinterpret_cast<const float4*>(sp);
            b2H = *reinterpret_cast<const float4*>(sp + 4);
        }
    };
    auto WRITES = [&]() {
#pragma unroll
        for (int p = 0; p < 2; ++p) {
            int r = srow + 56 * p;
            ssA[p] += sumsq4(aL[p]) + sumsq4(aH[p]);
            *reinterpret_cast<bf16x8*>(&lds[r * 64 + ((sslt ^ (r & 7)) << 3)]) =
                f4x2_to_bf8(aL[p], aH[p]);
        }
        {
            int r = srow;
            ssB += sumsq4(bL) + sumsq4(bH);
            *reinterpret_cast<bf16x8*>(&lds[7168 + r * 64 + ((sslt ^ (r & 7)) << 3)]) =
                f4x2_to_bf8(bL, bH);
        }
        if (tid < 64) {
            int r = 56 + srow;
            ssB2 += sumsq4(b2L) + sumsq4(b2H);
            *reinterpret_cast<bf16x8*>(&lds[7168 + r * 64 + ((sslt ^ (r & 7)) << 3)]) =
                f4x2_to_bf8(b2L, b2H);
        }
    };

    f32x4 acc[4];
#pragma unroll
    for (int j = 0; j < 4; ++j) acc[j] = f32x4{0.f, 0.f, 0.f, 0.f};

    LOADS(0);
    for (int kt = 0; kt < 12; ++kt) {
        if (kt) __syncthreads();
        WRITES();
        __syncthreads();
        if (kt < 11) LOADS((kt + 1) * 64);
#pragma unroll
        for (int ks = 0; ks < 2; ++ks) {
            bf16x8 af, bf[4];
            {
                int r = w * 16 + l16;
                af = *reinterpret_cast<const bf16x8*>(
                    &lds[r * 64 + (((ks * 4 + q) ^ (r & 7)) << 3)]);
            }
#pragma unroll
            for (int ct = 0; ct < 4; ++ct) {
                int r = ct * 16 + l16;
                bf[ct] = *reinterpret_cast<const bf16x8*>(
                    &lds[7168 + r * 64 + (((ks * 4 + q) ^ (r & 7)) << 3)]);
            }
#pragma unroll
            for (int ct = 0; ct < 4; ++ct)
                acc[ct] = __builtin_amdgcn_mfma_f32_16x16x32_bf16(af, bf[ct], acc[ct], 0, 0, 0);
        }
    }
    __syncthreads();

#pragma unroll
    for (int p = 0; p < 2; ++p) ldsF[(srow + 56 * p) * 8 + sslt] = ssA[p];
    ldsF[896 + srow * 8 + sslt] = ssB;
    if (tid < 64) ldsF[896 + (56 + srow) * 8 + sslt] = ssB2;
    __syncthreads();

    float ivy[4];
#pragma unroll
    for (int ct = 0; ct < 4; ++ct) {
        int jr = ct * 16 + l16;
        f32x4 s0 = *reinterpret_cast<const f32x4*>(&ldsF[896 + jr * 8]);
        f32x4 s1 = *reinterpret_cast<const f32x4*>(&ldsF[896 + jr * 8 + 4]);
        float ss = (s0.x + s0.y) + (s0.z + s0.w) + (s1.x + s1.y) + (s1.z + s1.w);
        ivy[ct] = 1.0f / (sqrtf(ss) + 1e-12f);
    }
#pragma unroll
    for (int rr = 0; rr < 4; ++rr) {
        int i = w * 16 + q * 4 + rr;
        int gi = r0 + i;
        if (gi < NSP) {
            f32x4 s0 = *reinterpret_cast<const f32x4*>(&ldsF[i * 8]);
            f32x4 s1 = *reinterpret_cast<const f32x4*>(&ldsF[i * 8 + 4]);
            float ss = (s0.x + s0.y) + (s0.z + s0.w) + (s1.x + s1.y) + (s1.z + s1.w);
            float ivx = 1.0f / (sqrtf(ss) + 1e-12f);
#pragma unroll
            for (int ct = 0; ct < 4; ++ct) {
                float cs = acc[ct][rr] * ivx * ivy[ct];
                Aout[(size_t)b * 65536 + (size_t)gi * 256 + (n0 + ct * 16 + l16)] =
                    (__bf16)__expf(2.0f * cs - 2.0f);
            }
        }
    }
}

// ---------------- temporal cost GEMM (f32 in/out) ----------------
template<int WROWS, int NWAVES, int BN, int NPTS>
__global__ __launch_bounds__(NWAVES * 64)
void cost_gemm(const float* __restrict__ X, const float* __restrict__ Y,
               const float* __restrict__ invx, const float* __restrict__ invy,
               float* __restrict__ Aout)
{
    constexpr int MT = WROWS * NWAVES;
    constexpr int CT = BN / 16;
    constexpr int RT = WROWS / 16;
    constexpr int KP = 40;
    constexpr int NTH = NWAVES * 64;
    __shared__ __bf16 As[MT][KP];
    __shared__ __bf16 Bs[BN][KP];

    const int b    = blockIdx.y;
    const int row0 = blockIdx.x * MT;
    const int tid  = threadIdx.x;
    const int w    = tid >> 6, lane = tid & 63;
    const int q    = lane >> 4, l16 = lane & 15;
    const float* Xb = X + (size_t)b * NPTS * DDIM;
    const float* Yb = Y + (size_t)b * NPTS * DDIM;

    f32x4 acc[RT][CT];
#pragma unroll
    for (int i = 0; i < RT; ++i)
#pragma unroll
        for (int j = 0; j < CT; ++j) acc[i][j] = f32x4{0.f, 0.f, 0.f, 0.f};

    for (int k0 = 0; k0 < DDIM; k0 += 32) {
        __syncthreads();
        for (int idx = tid * 4; idx < MT * 32; idx += NTH * 4) {
            int r = idx >> 5, kk = idx & 31;
            int gr = row0 + r;
            float4 v = {0.f, 0.f, 0.f, 0.f};
            if (gr < NPTS) v = *reinterpret_cast<const float4*>(Xb + (size_t)gr * DDIM + k0 + kk);
            *reinterpret_cast<ushort4*>(&As[r][kk]) = f4_to_bf4(v);
        }
        for (int idx = tid * 4; idx < BN * 32; idx += NTH * 4) {
            int r = idx >> 5, kk = idx & 31;
            float4 v = {0.f, 0.f, 0.f, 0.f};
            if (r < NPTS) v = *reinterpret_cast<const float4*>(Yb + (size_t)r * DDIM + k0 + kk);
            *reinterpret_cast<ushort4*>(&Bs[r][kk]) = f4_to_bf4(v);
        }
        __syncthreads();

        bf16x8 af[RT];
#pragma unroll
        for (int rt = 0; rt < RT; ++rt)
            af[rt] = *reinterpret_cast<const bf16x8*>(&As[w * WROWS + rt * 16 + l16][q * 8]);
#pragma unroll
        for (int ct = 0; ct < CT; ++ct) {
            bf16x8 bfr = *reinterpret_cast<const bf16x8*>(&Bs[ct * 16 + l16][q * 8]);
#pragma unroll
            for (int rt = 0; rt < RT; ++rt)
                acc[rt][ct] = __builtin_amdgcn_mfma_f32_16x16x32_bf16(af[rt], bfr, acc[rt][ct], 0, 0, 0);
        }
    }

#pragma unroll
    for (int rt = 0; rt < RT; ++rt)
#pragma unroll
        for (int ct = 0; ct < CT; ++ct)
#pragma unroll
            for (int rr = 0; rr < 4; ++rr) {
                int i = row0 + w * WROWS + rt * 16 + q * 4 + rr;
                int j = ct * 16 + l16;
                if (i < NPTS && j < NPTS) {
                    float g  = acc[rt][ct][rr];
                    float cs = g * invx[b * NPTS + i] * invy[b * NPTS + j];
                    Aout[(size_t)b * NPTS * NPTS + (size_t)i * NPTS + j] = expf(-2.0f * (1.0f - cs));
                }
            }
}

// ====== fused IPOT v9: A in REGISTERS (packed bf16), LDS only for reduce =====
// Spatial blocks 0..127 (512 thr), temporal 128..255 (1 wave, verified).
// Lane (w, rq, cl): rows g+32k (k<7, g=w*4+rq), cols {8cl+e, 8cl+128+e}.
// A loaded once from global into 14 packed bf16x8 regs (masked at load for
// rows/cols >= 196 -> replaces staging-time masking; A_sp pad is garbage).
// Iteration loop touches LDS only for cpart/svec. Same verified recursion.
__global__ __launch_bounds__(512, 1)
void ipot_reg(const __bf16* __restrict__ Asp, const float* __restrict__ Atm,
              float* __restrict__ out)
{
    __shared__ float cpart[32 * 260];     // 33,280 B
    __shared__ float svec[2][272];
    __shared__ float wsum[8];

    const int B = blockIdx.x;
    if (B >= 128) {
        if (threadIdx.x >= 64) return;
        const int b = B - 128;
        const float* Ab = Atm + (size_t)b * NTM * NTM;
        const int lane = threadIdx.x;
        const int rh = lane >> 5, cj = lane & 31;
        constexpr float MIU = 1.f / NTM;
        float A[16], P[16];
#pragma unroll
        for (int k = 0; k < 16; ++k) {
            A[k] = Ab[(rh + 2 * k) * NTM + cj];
            P[k] = 1.f;
        }
        float sv = MIU;
        for (int it = 0; it < 20; ++it) {
#pragma unroll
            for (int k = 0; k < 16; ++k) {
                P[k] *= A[k];
                float acc = row16_sum(P[k] * sv);
                acc += __shfl_xor(acc, 16);
                P[k] *= MIU * __builtin_amdgcn_rcpf(acc + 1e-6f);
            }
            float cssum = 0.f;
#pragma unroll
            for (int k = 0; k < 16; ++k) cssum += P[k];
            cssum += __shfl_xor(cssum, 32);
            float sg = MIU * __builtin_amdgcn_rcpf(cssum + 1e-6f);
#pragma unroll
            for (int k = 0; k < 16; ++k) P[k] *= sg;
            sv = sg;
        }
        float acc = 0.f;
#pragma unroll
        for (int k = 0; k < 16; ++k)
            acc = fmaf(P[k], -0.5f * __logf(A[k]), acc);
        acc = row16_sum(acc);
        acc += __shfl_xor(acc, 16);
        acc += __shfl_xor(acc, 32);
        if (lane == 0) atomicAdd(out, -acc * (1.f / BS));
        return;
    }

    const int b = (B & 7) * 16 + (B >> 3);
    const __bf16* Ab = Asp + (size_t)b * 65536;
    const int tid = threadIdx.x;
    const int w = tid >> 6, lane = tid & 63;
    const int rq = lane >> 4, cl = lane & 15;
    const int g = w * 4 + rq;
    const int colbase = cl * 8;
    constexpr float MIU = 1.f / NSP;

    // ---- load A into registers (masked) ----
    bf16x8 A0[7], A1[7];
    bf16x8 zero8;
#pragma unroll
    for (int i = 0; i < 8; ++i) zero8[i] = (__bf16)0.f;
#pragma unroll
    for (int k = 0; k < 7; ++k) {
        int row = g + 32 * k;
        bool rv = (row < NSP);
        const __bf16* ap = Ab + (size_t)row * 256 + colbase;
        bf16x8 a0 = rv ? *reinterpret_cast<const bf16x8*>(ap) : zero8;
        bf16x8 a1 = rv ? *reinterpret_cast<const bf16x8*>(ap + 128) : zero8;
#pragma unroll
        for (int e = 0; e < 8; ++e)
            if (128 + colbase + e >= NSP) a1[e] = (__bf16)0.f;
        A0[k] = a0;
        A1[k] = a1;
    }

    float P[7][16];
#pragma unroll
    for (int k = 0; k < 7; ++k)
#pragma unroll
        for (int e = 0; e < 16; ++e) P[k][e] = 1.f;

    float sr[16];
#pragma unroll
    for (int e = 0; e < 16; ++e) {
        int j = (e < 8) ? (colbase + e) : (colbase + 128 + (e - 8));
        sr[e] = (j < NSP) ? MIU : 0.f;
    }

    for (int it = 0; it < 20; ++it) {
        float cs[16];
#pragma unroll
        for (int e = 0; e < 16; ++e) cs[e] = 0.f;

#pragma unroll
        for (int k = 0; k < 7; ++k) {
            float r0 = 0.f, r1 = 0.f;
#pragma unroll
            for (int e = 0; e < 8; ++e) {
                P[k][e] *= (float)A0[k][e];
                r0 = fmaf(P[k][e], sr[e], r0);
            }
#pragma unroll
            for (int e = 0; e < 8; ++e) {
                P[k][8 + e] *= (float)A1[k][e];
                r1 = fmaf(P[k][8 + e], sr[8 + e], r1);
            }
            float racc = row16_sum(r0 + r1);
            float delta = MIU * __builtin_amdgcn_rcpf(racc + 1e-6f);
#pragma unroll
            for (int e = 0; e < 16; ++e) {
                P[k][e] *= delta;
                cs[e] += P[k][e];
            }
        }
        {
            float* cp = &cpart[g * 260 + colbase];
            *reinterpret_cast<f32x4*>(cp)       = f32x4{cs[0], cs[1], cs[2], cs[3]};
            *reinterpret_cast<f32x4*>(cp + 4)   = f32x4{cs[4], cs[5], cs[6], cs[7]};
            *reinterpret_cast<f32x4*>(cp + 128) = f32x4{cs[8], cs[9], cs[10], cs[11]};
            *reinterpret_cast<f32x4*>(cp + 132) = f32x4{cs[12], cs[13], cs[14], cs[15]};
        }
        __syncthreads();
        if (tid < 256) {
            float s0 = 0.f, s1 = 0.f, s2 = 0.f, s3 = 0.f;
#pragma unroll
            for (int gg = 0; gg < 32; gg += 4) {
                s0 += cpart[(gg + 0) * 260 + tid];
                s1 += cpart[(gg + 1) * 260 + tid];
                s2 += cpart[(gg + 2) * 260 + tid];
                s3 += cpart[(gg + 3) * 260 + tid];
            }
            float sum = (s0 + s1) + (s2 + s3);
            svec[it & 1][tid] = (tid < NSP) ? (MIU * __builtin_amdgcn_rcpf(sum + 1e-6f)) : 0.f;
        }
        __syncthreads();
        {
            const float* sv = svec[it & 1];
            f32x4 t0 = *reinterpret_cast<const f32x4*>(&sv[colbase]);
            f32x4 t1 = *reinterpret_cast<const f32x4*>(&sv[colbase + 4]);
            f32x4 t2 = *reinterpret_cast<const f32x4*>(&sv[colbase + 128]);
            f32x4 t3 = *reinterpret_cast<const f32x4*>(&sv[colbase + 132]);
            sr[0] = t0.x; sr[1] = t0.y; sr[2] = t0.z; sr[3] = t0.w;
            sr[4] = t1.x; sr[5] = t1.y; sr[6] = t1.z; sr[7] = t1.w;
            sr[8] = t2.x; sr[9] = t2.y; sr[10] = t2.z; sr[11] = t2.w;
            sr[12] = t3.x; sr[13] = t3.y; sr[14] = t3.z; sr[15] = t3.w;
        }
#pragma unroll
        for (int k = 0; k < 7; ++k)
#pragma unroll
            for (int e = 0; e < 16; ++e) P[k][e] *= sr[e];
    }

    // loss: -sum T*C, C = -0.5*log(A)
    float acc = 0.f;
#pragma unroll
    for (int k = 0; k < 7; ++k) {
#pragma unroll
        for (int e = 0; e < 8; ++e) {
            acc = fmaf(P[k][e],     -0.5f * __logf(fmaxf((float)A0[k][e], 1e-30f)), acc);
            acc = fmaf(P[k][8 + e], -0.5f * __logf(fmaxf((float)A1[k][e], 1e-30f)), acc);
        }
    }
    acc = row16_sum(acc);
    acc += __shfl_xor(acc, 16);
    acc += __shfl_xor(acc, 32);
    if (lane == 0) wsum[w] = acc;
    __syncthreads();
    if (tid == 0) {
        float t = 0.f;
#pragma unroll
        for (int i = 0; i < 8; ++i) t += wsum[i];
        atomicAdd(out, -t * (1.f / BS));
    }
}

extern "C" void kernel_launch(void* const* d_in, const int* in_sizes, int n_in,
                              void* d_out, int out_size, void* d_ws, size_t ws_size,
                              hipStream_t stream)
{
    const float* sp1 = (const float*)d_in[0];
    const float* sp2 = (const float*)d_in[1];
    const float* tm1 = (const float*)d_in[2];
    const float* tm2 = (const float*)d_in[3];
    float* out = (float*)d_out;
    float* ws  = (float*)d_ws;

    float* inx_tm = ws;                          // 4096
    float* iny_tm = inx_tm + BS * NTM;           // 4096
    float* A_tm   = iny_tm + BS * NTM;           // 131072 f32
    __bf16* A_sp  = (__bf16*)(ws + 139264);      // 128*256*256 bf16 = 33,554,432 B

    tm_norm_kernel<<<dim3(2048), 256, 0, stream>>>(tm1, tm2, inx_tm, iny_tm);

    cost_gemm_sp2<<<dim3(1024), 448, 0, stream>>>(sp1, sp2, A_sp);

    cost_gemm<16, 2, 32, NTM><<<dim3(1, BS), 128, 0, stream>>>(tm1, tm2, inx_tm, iny_tm, A_tm);

    (void)hipMemsetAsync(d_out, 0, sizeof(float), stream);

    ipot_reg<<<dim3(256), 512, 0, stream>>>(A_sp, A_tm, out);
}

// Round 24
// 147.057 us; speedup vs baseline: 1.1226x; 1.0514x over previous
//
#include <hip/hip_runtime.h>
#include <hip/hip_bf16.h>
#include <cstdint>

typedef float f32x4 __attribute__((ext_vector_type(4)));
typedef __bf16 bf16x8 __attribute__((ext_vector_type(8)));

#define BS 128
#define NSP 196
#define NTM 32
#define DDIM 768

__device__ inline ushort4 f4_to_bf4(float4 v)
{
    ushort4 u;
    u.x = __builtin_bit_cast(unsigned short, (__bf16)v.x);
    u.y = __builtin_bit_cast(unsigned short, (__bf16)v.y);
    u.z = __builtin_bit_cast(unsigned short, (__bf16)v.z);
    u.w = __builtin_bit_cast(unsigned short, (__bf16)v.w);
    return u;
}

__device__ inline bf16x8 f4x2_to_bf8(float4 lo, float4 hi)
{
    bf16x8 r;
    r[0] = (__bf16)lo.x; r[1] = (__bf16)lo.y; r[2] = (__bf16)lo.z; r[3] = (__bf16)lo.w;
    r[4] = (__bf16)hi.x; r[5] = (__bf16)hi.y; r[6] = (__bf16)hi.z; r[7] = (__bf16)hi.w;
    return r;
}

__device__ inline float sumsq4(float4 a)
{
    return fmaf(a.x, a.x, fmaf(a.y, a.y, fmaf(a.z, a.z, a.w * a.w)));
}

// sum over the 16-lane DPP row; every lane gets the total.
__device__ inline float row16_sum(float x)
{
    int t;
    t = __builtin_amdgcn_update_dpp(0, __builtin_bit_cast(int, x), 0x121, 0xf, 0xf, true);
    x += __builtin_bit_cast(float, t);
    t = __builtin_amdgcn_update_dpp(0, __builtin_bit_cast(int, x), 0x122, 0xf, 0xf, true);
    x += __builtin_bit_cast(float, t);
    t = __builtin_amdgcn_update_dpp(0, __builtin_bit_cast(int, x), 0x124, 0xf, 0xf, true);
    x += __builtin_bit_cast(float, t);
    t = __builtin_amdgcn_update_dpp(0, __builtin_bit_cast(int, x), 0x128, 0xf, 0xf, true);
    x += __builtin_bit_cast(float, t);
    return x;
}

// ---------------- temporal row inverse-norms only ----------------
__global__ __launch_bounds__(256)
void tm_norm_kernel(const float* __restrict__ tm1, const float* __restrict__ tm2,
                    float* __restrict__ inx_tm, float* __restrict__ iny_tm)
{
    int B = blockIdx.x;
    const float* src; float* inv;
    if (B < 1024) { src = tm1; inv = inx_tm; }
    else          { B -= 1024; src = tm2; inv = iny_tm; }
    const int row  = B * 4 + (threadIdx.x >> 6);
    const int lane = threadIdx.x & 63;
    const float4* p = reinterpret_cast<const float4*>(src + (size_t)row * DDIM);
    float ss = 0.f;
#pragma unroll
    for (int c = 0; c < 3; ++c) ss += sumsq4(p[lane + 64 * c]);
#pragma unroll
    for (int off = 32; off; off >>= 1) ss += __shfl_xor(ss, off, 64);
    if (lane == 0) inv[row] = 1.0f / (sqrtf(ss) + 1e-12f);
}

// ============== spatial cost GEMM (verified R16: best config) ==============
// 112-row tiles, grid 1024 = 8 XCD * 16 batch * 2 rowtile * 4 coltile.
// Block 448 thr (7 waves), RT=1, 22.5KB single LDS buffer (4 blocks/CU),
// fused row-norm sumsq during staging, XOR slot swizzle.
__global__ __launch_bounds__(448)
void cost_gemm_sp2(const float* __restrict__ X, const float* __restrict__ Y,
                   __bf16* __restrict__ Aout)
{
    __shared__ __bf16 lds[11264];          // A 112*64 + B 64*64 = 22,528 B
    float* ldsF = reinterpret_cast<float*>(lds);

    const int flat  = blockIdx.x;
    const int xcd   = flat & 7;
    const int s     = flat >> 3;           // 0..127
    const int b     = xcd * 16 + (s >> 3);
    const int rem   = s & 7;
    const int r0    = (rem >> 2) * 112;    // 0 or 112
    const int ct_   = rem & 3;
    const int n0    = (ct_ < 3) ? ct_ * 64 : 132;

    const int tid  = threadIdx.x;
    const int w    = tid >> 6, lane = tid & 63;
    const int q    = lane >> 4, l16 = lane & 15;
    const int srow = tid >> 3;          // 0..55
    const int sslt = tid & 7;           // 0..7

    const float* Yb = Y + (size_t)b * NSP * DDIM;

    float4 aL[2], aH[2], bL, bH, b2L, b2H;
    float ssA[2] = {0.f, 0.f};
    float ssB = 0.f, ssB2 = 0.f;

    auto LOADS = [&](int k0) {
#pragma unroll
        for (int p = 0; p < 2; ++p) {
            int gr = b * NSP + r0 + srow + 56 * p;
            gr = min(gr, BS * NSP - 1);              // clamp; masked at store
            const float* sp = X + (size_t)gr * DDIM + k0 + sslt * 8;
            aL[p] = *reinterpret_cast<const float4*>(sp);
            aH[p] = *reinterpret_cast<const float4*>(sp + 4);
        }
        {
            const float* sp = Yb + (size_t)(n0 + srow) * DDIM + k0 + sslt * 8;
            bL = *reinterpret_cast<const float4*>(sp);
            bH = *reinterpret_cast<const float4*>(sp + 4);
        }
        if (tid < 64) {
            const float* sp = Yb + (size_t)(n0 + 56 + srow) * DDIM + k0 + sslt * 8;
            b2L = *reinterpret_cast<const float4*>(sp);
            b2H = *reinterpret_cast<const float4*>(sp + 4);
        }
    };
    auto WRITES = [&]() {
#pragma unroll
        for (int p = 0; p < 2; ++p) {
            int r = srow + 56 * p;
            ssA[p] += sumsq4(aL[p]) + sumsq4(aH[p]);
            *reinterpret_cast<bf16x8*>(&lds[r * 64 + ((sslt ^ (r & 7)) << 3)]) =
                f4x2_to_bf8(aL[p], aH[p]);
        }
        {
            int r = srow;
            ssB += sumsq4(bL) + sumsq4(bH);
            *reinterpret_cast<bf16x8*>(&lds[7168 + r * 64 + ((sslt ^ (r & 7)) << 3)]) =
                f4x2_to_bf8(bL, bH);
        }
        if (tid < 64) {
            int r = 56 + srow;
            ssB2 += sumsq4(b2L) + sumsq4(b2H);
            *reinterpret_cast<bf16x8*>(&lds[7168 + r * 64 + ((sslt ^ (r & 7)) << 3)]) =
                f4x2_to_bf8(b2L, b2H);
        }
    };

    f32x4 acc[4];
#pragma unroll
    for (int j = 0; j < 4; ++j) acc[j] = f32x4{0.f, 0.f, 0.f, 0.f};

    LOADS(0);
    for (int kt = 0; kt < 12; ++kt) {
        if (kt) __syncthreads();
        WRITES();
        __syncthreads();
        if (kt < 11) LOADS((kt + 1) * 64);
#pragma unroll
        for (int ks = 0; ks < 2; ++ks) {
            bf16x8 af, bf[4];
            {
                int r = w * 16 + l16;
                af = *reinterpret_cast<const bf16x8*>(
                    &lds[r * 64 + (((ks * 4 + q) ^ (r & 7)) << 3)]);
            }
#pragma unroll
            for (int ct = 0; ct < 4; ++ct) {
                int r = ct * 16 + l16;
                bf[ct] = *reinterpret_cast<const bf16x8*>(
                    &lds[7168 + r * 64 + (((ks * 4 + q) ^ (r & 7)) << 3)]);
            }
#pragma unroll
            for (int ct = 0; ct < 4; ++ct)
                acc[ct] = __builtin_amdgcn_mfma_f32_16x16x32_bf16(af, bf[ct], acc[ct], 0, 0, 0);
        }
    }
    __syncthreads();

    // ---- reduce norm partials through the (now free) LDS buffer ----
#pragma unroll
    for (int p = 0; p < 2; ++p) ldsF[(srow + 56 * p) * 8 + sslt] = ssA[p];
    ldsF[896 + srow * 8 + sslt] = ssB;
    if (tid < 64) ldsF[896 + (56 + srow) * 8 + sslt] = ssB2;
    __syncthreads();

    float ivy[4];
#pragma unroll
    for (int ct = 0; ct < 4; ++ct) {
        int jr = ct * 16 + l16;
        f32x4 s0 = *reinterpret_cast<const f32x4*>(&ldsF[896 + jr * 8]);
        f32x4 s1 = *reinterpret_cast<const f32x4*>(&ldsF[896 + jr * 8 + 4]);
        float ss = (s0.x + s0.y) + (s0.z + s0.w) + (s1.x + s1.y) + (s1.z + s1.w);
        ivy[ct] = 1.0f / (sqrtf(ss) + 1e-12f);
    }
#pragma unroll
    for (int rr = 0; rr < 4; ++rr) {
        int i = w * 16 + q * 4 + rr;
        int gi = r0 + i;
        if (gi < NSP) {
            f32x4 s0 = *reinterpret_cast<const f32x4*>(&ldsF[i * 8]);
            f32x4 s1 = *reinterpret_cast<const f32x4*>(&ldsF[i * 8 + 4]);
            float ss = (s0.x + s0.y) + (s0.z + s0.w) + (s1.x + s1.y) + (s1.z + s1.w);
            float ivx = 1.0f / (sqrtf(ss) + 1e-12f);
#pragma unroll
            for (int ct = 0; ct < 4; ++ct) {
                float cs = acc[ct][rr] * ivx * ivy[ct];
                Aout[(size_t)b * 65536 + (size_t)gi * 256 + (n0 + ct * 16 + l16)] =
                    (__bf16)__expf(2.0f * cs - 2.0f);
            }
        }
    }
}

// ---------------- temporal cost GEMM (f32 in/out) ----------------
template<int WROWS, int NWAVES, int BN, int NPTS>
__global__ __launch_bounds__(NWAVES * 64)
void cost_gemm(const float* __restrict__ X, const float* __restrict__ Y,
               const float* __restrict__ invx, const float* __restrict__ invy,
               float* __restrict__ Aout)
{
    constexpr int MT = WROWS * NWAVES;
    constexpr int CT = BN / 16;
    constexpr int RT = WROWS / 16;
    constexpr int KP = 40;
    constexpr int NTH = NWAVES * 64;
    __shared__ __bf16 As[MT][KP];
    __shared__ __bf16 Bs[BN][KP];

    const int b    = blockIdx.y;
    const int row0 = blockIdx.x * MT;
    const int tid  = threadIdx.x;
    const int w    = tid >> 6, lane = tid & 63;
    const int q    = lane >> 4, l16 = lane & 15;
    const float* Xb = X + (size_t)b * NPTS * DDIM;
    const float* Yb = Y + (size_t)b * NPTS * DDIM;

    f32x4 acc[RT][CT];
#pragma unroll
    for (int i = 0; i < RT; ++i)
#pragma unroll
        for (int j = 0; j < CT; ++j) acc[i][j] = f32x4{0.f, 0.f, 0.f, 0.f};

    for (int k0 = 0; k0 < DDIM; k0 += 32) {
        __syncthreads();
        for (int idx = tid * 4; idx < MT * 32; idx += NTH * 4) {
            int r = idx >> 5, kk = idx & 31;
            int gr = row0 + r;
            float4 v = {0.f, 0.f, 0.f, 0.f};
            if (gr < NPTS) v = *reinterpret_cast<const float4*>(Xb + (size_t)gr * DDIM + k0 + kk);
            *reinterpret_cast<ushort4*>(&As[r][kk]) = f4_to_bf4(v);
        }
        for (int idx = tid * 4; idx < BN * 32; idx += NTH * 4) {
            int r = idx >> 5, kk = idx & 31;
            float4 v = {0.f, 0.f, 0.f, 0.f};
            if (r < NPTS) v = *reinterpret_cast<const float4*>(Yb + (size_t)r * DDIM + k0 + kk);
            *reinterpret_cast<ushort4*>(&Bs[r][kk]) = f4_to_bf4(v);
        }
        __syncthreads();

        bf16x8 af[RT];
#pragma unroll
        for (int rt = 0; rt < RT; ++rt)
            af[rt] = *reinterpret_cast<const bf16x8*>(&As[w * WROWS + rt * 16 + l16][q * 8]);
#pragma unroll
        for (int ct = 0; ct < CT; ++ct) {
            bf16x8 bfr = *reinterpret_cast<const bf16x8*>(&Bs[ct * 16 + l16][q * 8]);
#pragma unroll
            for (int rt = 0; rt < RT; ++rt)
                acc[rt][ct] = __builtin_amdgcn_mfma_f32_16x16x32_bf16(af[rt], bfr, acc[rt][ct], 0, 0, 0);
        }
    }

#pragma unroll
    for (int rt = 0; rt < RT; ++rt)
#pragma unroll
        for (int ct = 0; ct < CT; ++ct)
#pragma unroll
            for (int rr = 0; rr < 4; ++rr) {
                int i = row0 + w * WROWS + rt * 16 + q * 4 + rr;
                int j = ct * 16 + l16;
                if (i < NPTS && j < NPTS) {
                    float g  = acc[rt][ct][rr];
                    float cs = g * invx[b * NPTS + i] * invy[b * NPTS + j];
                    Aout[(size_t)b * NPTS * NPTS + (size_t)i * NPTS + j] = expf(-2.0f * (1.0f - cs));
                }
            }
}

// ====== fused IPOT (R16-verified): DPP rowsum, 512 thr, A in LDS ======
__global__ __launch_bounds__(512, 1)
void ipot_dpp(const __bf16* __restrict__ Asp, const float* __restrict__ Atm,
              float* __restrict__ out)
{
    __shared__ __bf16 Alds[224 * 256];    // 114,688 B
    __shared__ float  cpart[32 * 260];    //  33,280 B
    __shared__ float  svec[2][272];
    __shared__ float  wsum[8];

    const int B = blockIdx.x;
    if (B >= 128) {
        if (threadIdx.x >= 64) return;
        const int b = B - 128;
        const float* Ab = Atm + (size_t)b * NTM * NTM;
        const int lane = threadIdx.x;
        const int rh = lane >> 5, cj = lane & 31;
        constexpr float MIU = 1.f / NTM;
        float A[16], P[16];
#pragma unroll
        for (int k = 0; k < 16; ++k) {
            A[k] = Ab[(rh + 2 * k) * NTM + cj];
            P[k] = 1.f;
        }
        float sv = MIU;
        for (int it = 0; it < 20; ++it) {
#pragma unroll
            for (int k = 0; k < 16; ++k) {
                P[k] *= A[k];
                float acc = row16_sum(P[k] * sv);
                acc += __shfl_xor(acc, 16);
                P[k] *= MIU * __builtin_amdgcn_rcpf(acc + 1e-6f);
            }
            float cssum = 0.f;
#pragma unroll
            for (int k = 0; k < 16; ++k) cssum += P[k];
            cssum += __shfl_xor(cssum, 32);
            float sg = MIU * __builtin_amdgcn_rcpf(cssum + 1e-6f);
#pragma unroll
            for (int k = 0; k < 16; ++k) P[k] *= sg;
            sv = sg;
        }
        float acc = 0.f;
#pragma unroll
        for (int k = 0; k < 16; ++k)
            acc = fmaf(P[k], -0.5f * __logf(A[k]), acc);
        acc = row16_sum(acc);
        acc += __shfl_xor(acc, 16);
        acc += __shfl_xor(acc, 32);
        if (lane == 0) atomicAdd(out, -acc * (1.f / BS));
        return;
    }

    const int b = (B & 7) * 16 + (B >> 3);
    const __bf16* Ab = Asp + (size_t)b * 65536;
    const int tid = threadIdx.x;
    const int w = tid >> 6, lane = tid & 63;
    const int rq = lane >> 4, cl = lane & 15;
    const int g = w * 4 + rq;
    const int colbase = cl * 8;
    constexpr float MIU = 1.f / NSP;

    for (int idx = tid; idx < NSP * 32; idx += 512) {
        int r = idx >> 5, c = idx & 31;
        bf16x8 v;
#pragma unroll
        for (int i = 0; i < 8; ++i) v[i] = (__bf16)0.f;
        if (c < 25) {
            v = *reinterpret_cast<const bf16x8*>(&Ab[(size_t)r * 256 + c * 8]);
            if (c == 24) { v[4] = (__bf16)0.f; v[5] = (__bf16)0.f; v[6] = (__bf16)0.f; v[7] = (__bf16)0.f; }
        }
        *reinterpret_cast<bf16x8*>(&Alds[r * 256 + c * 8]) = v;
    }
    {
        ushort4 z = {0, 0, 0, 0};
        for (int idx = tid; idx < 28 * 64; idx += 512) {
            int r = 196 + (idx >> 6), c4 = (idx & 63) << 2;
            *reinterpret_cast<ushort4*>(&Alds[r * 256 + c4]) = z;
        }
    }
    __syncthreads();

    float P[7][16];
#pragma unroll
    for (int k = 0; k < 7; ++k)
#pragma unroll
        for (int e = 0; e < 16; ++e) P[k][e] = 1.f;

    float sr[16];
#pragma unroll
    for (int e = 0; e < 16; ++e) {
        int j = (e < 8) ? (colbase + e) : (colbase + 128 + (e - 8));
        sr[e] = (j < NSP) ? MIU : 0.f;
    }

    for (int it = 0; it < 20; ++it) {
        float cs[16];
#pragma unroll
        for (int e = 0; e < 16; ++e) cs[e] = 0.f;

#pragma unroll
        for (int k = 0; k < 7; ++k) {
            const __bf16* ap = &Alds[(g + 32 * k) * 256 + colbase];
            bf16x8 a0 = *reinterpret_cast<const bf16x8*>(ap);
            bf16x8 a1 = *reinterpret_cast<const bf16x8*>(ap + 128);
            float r0 = 0.f, r1 = 0.f;
#pragma unroll
            for (int e = 0; e < 8; ++e) {
                P[k][e] *= (float)a0[e];
                r0 = fmaf(P[k][e], sr[e], r0);
            }
#pragma unroll
            for (int e = 0; e < 8; ++e) {
                P[k][8 + e] *= (float)a1[e];
                r1 = fmaf(P[k][8 + e], sr[8 + e], r1);
            }
            float racc = row16_sum(r0 + r1);
            float delta = MIU * __builtin_amdgcn_rcpf(racc + 1e-6f);
#pragma unroll
            for (int e = 0; e < 16; ++e) {
                P[k][e] *= delta;
                cs[e] += P[k][e];
            }
        }
        {
            float* cp = &cpart[g * 260 + colbase];
            *reinterpret_cast<f32x4*>(cp)     = f32x4{cs[0], cs[1], cs[2], cs[3]};
            *reinterpret_cast<f32x4*>(cp + 4) = f32x4{cs[4], cs[5], cs[6], cs[7]};
            float* cp2 = cp + 128;
            *reinterpret_cast<f32x4*>(cp2)     = f32x4{cs[8], cs[9], cs[10], cs[11]};
            *reinterpret_cast<f32x4*>(cp2 + 4) = f32x4{cs[12], cs[13], cs[14], cs[15]};
        }
        __syncthreads();
        if (tid < 256) {
            float s0 = 0.f, s1 = 0.f, s2 = 0.f, s3 = 0.f;
#pragma unroll
            for (int gg = 0; gg < 32; gg += 4) {
                s0 += cpart[(gg + 0) * 260 + tid];
                s1 += cpart[(gg + 1) * 260 + tid];
                s2 += cpart[(gg + 2) * 260 + tid];
                s3 += cpart[(gg + 3) * 260 + tid];
            }
            float sum = (s0 + s1) + (s2 + s3);
            svec[it & 1][tid] = (tid < NSP) ? (MIU * __builtin_amdgcn_rcpf(sum + 1e-6f)) : 0.f;
        }
        __syncthreads();
        {
            const float* sv = svec[it & 1];
            f32x4 t0 = *reinterpret_cast<const f32x4*>(&sv[colbase]);
            f32x4 t1 = *reinterpret_cast<const f32x4*>(&sv[colbase + 4]);
            f32x4 t2 = *reinterpret_cast<const f32x4*>(&sv[colbase + 128]);
            f32x4 t3 = *reinterpret_cast<const f32x4*>(&sv[colbase + 132]);
            sr[0] = t0.x; sr[1] = t0.y; sr[2] = t0.z; sr[3] = t0.w;
            sr[4] = t1.x; sr[5] = t1.y; sr[6] = t1.z; sr[7] = t1.w;
            sr[8] = t2.x; sr[9] = t2.y; sr[10] = t2.z; sr[11] = t2.w;
            sr[12] = t3.x; sr[13] = t3.y; sr[14] = t3.z; sr[15] = t3.w;
        }
#pragma unroll
        for (int k = 0; k < 7; ++k)
#pragma unroll
            for (int e = 0; e < 16; ++e) P[k][e] *= sr[e];
    }

    float acc = 0.f;
#pragma unroll
    for (int k = 0; k < 7; ++k) {
        const __bf16* ap = &Alds[(g + 32 * k) * 256 + colbase];
        bf16x8 a0 = *reinterpret_cast<const bf16x8*>(ap);
        bf16x8 a1 = *reinterpret_cast<const bf16x8*>(ap + 128);
#pragma unroll
        for (int e = 0; e < 8; ++e) {
            acc = fmaf(P[k][e],     -0.5f * __logf(fmaxf((float)a0[e], 1e-30f)), acc);
            acc = fmaf(P[k][8 + e], -0.5f * __logf(fmaxf((float)a1[e], 1e-30f)), acc);
        }
    }
    acc = row16_sum(acc);
    acc += __shfl_xor(acc, 16);
    acc += __shfl_xor(acc, 32);
    if (lane == 0) wsum[w] = acc;
    __syncthreads();
    if (tid == 0) {
        float t = 0.f;
#pragma unroll
        for (int i = 0; i < 8; ++i) t += wsum[i];
        atomicAdd(out, -t * (1.f / BS));
    }
}

extern "C" void kernel_launch(void* const* d_in, const int* in_sizes, int n_in,
                              void* d_out, int out_size, void* d_ws, size_t ws_size,
                              hipStream_t stream)
{
    const float* sp1 = (const float*)d_in[0];
    const float* sp2 = (const float*)d_in[1];
    const float* tm1 = (const float*)d_in[2];
    const float* tm2 = (const float*)d_in[3];
    float* out = (float*)d_out;
    float* ws  = (float*)d_ws;

    float* inx_tm = ws;                          // 4096
    float* iny_tm = inx_tm + BS * NTM;           // 4096
    float* A_tm   = iny_tm + BS * NTM;           // 131072 f32
    __bf16* A_sp  = (__bf16*)(ws + 139264);      // 128*256*256 bf16 = 33,554,432 B

    tm_norm_kernel<<<dim3(2048), 256, 0, stream>>>(tm1, tm2, inx_tm, iny_tm);

    cost_gemm_sp2<<<dim3(1024), 448, 0, stream>>>(sp1, sp2, A_sp);

    cost_gemm<16, 2, 32, NTM><<<dim3(1, BS), 128, 0, stream>>>(tm1, tm2, inx_tm, iny_tm, A_tm);

    (void)hipMemsetAsync(d_out, 0, sizeof(float), stream);

    ipot_dpp<<<dim3(256), 512, 0, stream>>>(A_sp, A_tm, out);
}